// Round 6
// baseline (674.917 us; speedup 1.0000x reference)
//
#include <hip/hip_runtime.h>

#define EPSILON 0.001f
#define NSUP 601
#define BLOCK_THREADS 256
#define NBLOCKS 4096                 // 16384 waves; 262144 rows -> 16 rows/wave

// Native clang vector type — __builtin_nontemporal_store rejects HIP's
// float4 (a HIP_vector_type class) but accepts this.
typedef float v4f __attribute__((ext_vector_type(4)));

// ---------------------------------------------------------------------------
// One wave per output row, grid-striding over rows. Two-hot values merged
// into the fill stream (no zero pass, no RMW, no barriers). vs round 4:
//   - ALL output stores nontemporal (`nt` flag): the 630 MB stream is
//     write-once, never re-read; nt avoids L2/L3 thrash on the way out.
// Structure (unchanged from R4):
//   - persistent grid (4096 wg), one wave per row, 16 rows/wave.
//   - v4f body with head/tail dwords: (row*601)%4 == row%4 -> head =
//     (4-row%4)&3 dwords, then 149-150 aligned 16B stores, then <=3 tail.
//   - t, lower, upper, p_low, p_high wave-uniform; x[row] broadcast load;
//     supports[] L1-resident.
//   - collision semantics: upper test taken first in the select chain, so at
//     the top clamp (lower==upper==600) p_high wins, matching the reference's
//     "upper overwrites lower" scatter order.
// ---------------------------------------------------------------------------
__global__ __launch_bounds__(BLOCK_THREADS)
void twohot_row_kernel(const float* __restrict__ x,
                       const float* __restrict__ supports,
                       float* __restrict__ out, int nrows, int nwaves_total) {
    const int wave = threadIdx.x >> 6;
    const int lane = threadIdx.x & 63;
    const int w0 = blockIdx.x * (BLOCK_THREADS / 64) + wave;

    for (int row = w0; row < nrows; row += nwaves_total) {
        const float v = x[row];
        const float s = (v > 0.f) ? 1.f : ((v < 0.f) ? -1.f : 0.f);
        const float t = s * (sqrtf(fabsf(v) + 1.f) - 1.f + EPSILON * v);

        // supports = linspace(-300,300,601), unit spacing:
        // searchsorted(right)-1 == floor(t)+300, clamped.
        int idx = (int)floorf(t) + 300;
        const int lower = idx < 0 ? 0 : (idx > NSUP - 1 ? NSUP - 1 : idx);
        const int upper = (lower + 1 > NSUP - 1) ? NSUP - 1 : lower + 1;

        const float ls = supports[lower];
        const float us = supports[upper];
        const float p_low = (us - t) / (us - ls);   // denom == 1.0 in-range
        const float p_high = 1.f - p_low;

        float* rp = out + (long long)row * NSUP;

        const int head = (4 - (row & 3)) & 3;       // dwords to 16B alignment
        const int nrem = NSUP - head;
        const int nf4 = nrem >> 2;                  // 149 or 150
        const int tail = nrem & 3;

        if (lane < head) {
            const int c = lane;
            const float val = (c == upper) ? p_high : ((c == lower) ? p_low : 0.f);
            __builtin_nontemporal_store(val, &rp[c]);
        }

        v4f* rp4 = (v4f*)(rp + head);               // 16B aligned by construction
        #pragma unroll
        for (int it = 0; it < 3; ++it) {
            const int f = it * 64 + lane;
            if (f < nf4) {
                const int c0 = head + f * 4;
                v4f val;
                val.x = (c0     == upper) ? p_high : ((c0     == lower) ? p_low : 0.f);
                val.y = (c0 + 1 == upper) ? p_high : ((c0 + 1 == lower) ? p_low : 0.f);
                val.z = (c0 + 2 == upper) ? p_high : ((c0 + 2 == lower) ? p_low : 0.f);
                val.w = (c0 + 3 == upper) ? p_high : ((c0 + 3 == lower) ? p_low : 0.f);
                __builtin_nontemporal_store(val, &rp4[f]);
            }
        }

        if (lane < tail) {
            const int c = head + nf4 * 4 + lane;
            const float val = (c == upper) ? p_high : ((c == lower) ? p_low : 0.f);
            __builtin_nontemporal_store(val, &rp[c]);
        }
    }
}

extern "C" void kernel_launch(void* const* d_in, const int* in_sizes, int n_in,
                              void* d_out, int out_size, void* d_ws, size_t ws_size,
                              hipStream_t stream) {
    const float* tv = (const float*)d_in[0];
    const float* supports = (const float*)d_in[1];
    float* out = (float*)d_out;

    const int nrows = in_sizes[0];                       // 4096*64 = 262144
    const int nwaves = NBLOCKS * (BLOCK_THREADS / 64);   // 16384
    twohot_row_kernel<<<NBLOCKS, BLOCK_THREADS, 0, stream>>>(
        tv, supports, out, nrows, nwaves);
}

// Round 7
// 633.370 us; speedup vs baseline: 1.0656x; 1.0656x over previous
//
#include <hip/hip_runtime.h>

#define EPSILON 0.001f
#define NSUP 601
#define BLOCK_THREADS 256
#define ROWS_PER_WAVE 16
#define F4_PER_WAVE 2404   // 16*601/4 — exact, and span start is 16B aligned

typedef float v4f __attribute__((ext_vector_type(4)));

// ---------------------------------------------------------------------------
// One wave per 16 consecutive rows (9616 floats == 2404 float4, aligned).
// Phase 1: branch-free dense dwordx4 zero-fill of the span — instruction
//          stream identical to __amd_rocclr_fillBufferAligned (no selects,
//          no masked head/tail; note: NO nt flag — R6 measured nt at -33%).
// Phase 2: __threadfence_block (per-wave vmcnt drain, no barrier), then 32
//          scattered dword stores (2 per row) into the wave's own span —
//          lines are L2-dirty from phase 1, stores merge, no HBM RMW.
// Params: every lane computes t/lower/upper/p for row 16w+(lane&15) —
//          redundant x4 but divergence-free, and guarantees valid registers
//          in all lanes for the __shfl gather in phase 2.
// Collision (top clamp, lower==upper==600): reference's upper-write wins;
//          here the lower-writing lane substitutes p_high when lower==upper,
//          so both colliding lanes write the same value — order-independent.
// ---------------------------------------------------------------------------
__global__ __launch_bounds__(BLOCK_THREADS)
void twohot_span_kernel(const float* __restrict__ x,
                        const float* __restrict__ supports,
                        float* __restrict__ out, int nrows) {
    const int wave_in_blk = threadIdx.x >> 6;
    const int lane = threadIdx.x & 63;
    const int w = blockIdx.x * (BLOCK_THREADS / 64) + wave_in_blk;  // global wave
    const int row0 = w * ROWS_PER_WAVE;
    if (row0 >= nrows) return;

    // --- per-row params, computed by all lanes for row0 + (lane&15) ---
    const int r = lane & 15;
    const float v = x[row0 + r];
    const float s = (v > 0.f) ? 1.f : ((v < 0.f) ? -1.f : 0.f);
    const float t = s * (sqrtf(fabsf(v) + 1.f) - 1.f + EPSILON * v);

    // supports = linspace(-300,300,601), unit spacing:
    // searchsorted(right)-1 == floor(t)+300, clamped.
    int idx = (int)floorf(t) + 300;
    const int lower = idx < 0 ? 0 : (idx > NSUP - 1 ? NSUP - 1 : idx);
    const int upper = (lower + 1 > NSUP - 1) ? NSUP - 1 : lower + 1;

    const float ls = supports[lower];
    const float us = supports[upper];
    const float p_low = (us - t) / (us - ls);       // denom == 1.0 in-range
    const float p_high = 1.f - p_low;
    // value the "lower" scatter lane writes: on collision both lanes write p_high
    const float pl_store = (lower == upper) ? p_high : p_low;

    // --- phase 1: dense zero-fill of the wave's span ---
    v4f* out4 = (v4f*)out + (long long)w * F4_PER_WAVE;
    const v4f z = (v4f)(0.f);
    #pragma unroll
    for (int i = 0; i < F4_PER_WAVE / 64; ++i) {    // 37 full iterations
        out4[i * 64 + lane] = z;
    }
    if (lane < F4_PER_WAVE % 64) {                  // tail: 36 lanes
        out4[(F4_PER_WAVE / 64) * 64 + lane] = z;
    }

    // --- order phase-1 stores before phase-2 stores (same wave, no barrier) ---
    __threadfence_block();

    // --- phase 2: 32 scattered dword stores (2 per row) ---
    if (lane < 2 * ROWS_PER_WAVE) {
        const int src = lane >> 1;                  // source row slot 0..15
        const int sel = lane & 1;                   // 0 -> lower, 1 -> upper
        const int lv = __shfl(lower, src);
        const int uv = __shfl(upper, src);
        const float plv = __shfl(pl_store, src);
        const float phv = __shfl(p_high, src);
        const int col = sel ? uv : lv;
        const float val = sel ? phv : plv;
        out[(long long)(row0 + src) * NSUP + col] = val;
    }
}

extern "C" void kernel_launch(void* const* d_in, const int* in_sizes, int n_in,
                              void* d_out, int out_size, void* d_ws, size_t ws_size,
                              hipStream_t stream) {
    const float* tv = (const float*)d_in[0];
    const float* supports = (const float*)d_in[1];
    float* out = (float*)d_out;

    const int nrows = in_sizes[0];                               // 262144
    const int nwaves = (nrows + ROWS_PER_WAVE - 1) / ROWS_PER_WAVE;  // 16384
    const int nblocks = (nwaves + 3) / 4;                        // 4096
    twohot_span_kernel<<<nblocks, BLOCK_THREADS, 0, stream>>>(tv, supports, out, nrows);
}